// Round 1
// baseline (1260.278 us; speedup 1.0000x reference)
//
#include <hip/hip_runtime.h>

#define N_NODES 100000
#define N_EDGES 1200000
#define DIM 64

// ---------------- degree histogram ----------------
__global__ __launch_bounds__(256) void deg_kernel(
    const int* __restrict__ src, const int* __restrict__ dst,
    float* __restrict__ deg_out, float* __restrict__ deg_in) {
  int e = blockIdx.x * 256 + threadIdx.x;
  if (e < N_EDGES) {
    unsafeAtomicAdd(&deg_out[src[e]], 1.0f);
    unsafeAtomicAdd(&deg_in[dst[e]], 1.0f);
  }
}

// ---------------- y = x @ W ----------------
// 64 rows per block, 256 threads; W and x-tile staged in LDS.
__global__ __launch_bounds__(256) void gemm_xw(
    const float* __restrict__ x, const float* __restrict__ W,
    float* __restrict__ y) {
  __shared__ float Ws[64][64];
  __shared__ float xs[64][64];
  int row0 = blockIdx.x * 64;

  const float4* W4 = (const float4*)W;
  float4* Ws4 = (float4*)&Ws[0][0];
  for (int i = threadIdx.x; i < 64 * 16; i += 256) Ws4[i] = W4[i];

  int nrows = N_NODES - row0;
  if (nrows > 64) nrows = 64;
  const float4* x4 = (const float4*)(x + (size_t)row0 * DIM);
  float4* xs4 = (float4*)&xs[0][0];
  for (int i = threadIdx.x; i < nrows * 16; i += 256) xs4[i] = x4[i];
  __syncthreads();

  int col = threadIdx.x & 63;
  int rg = threadIdx.x >> 6;  // 0..3
  for (int r = rg; r < nrows; r += 4) {
    float acc = 0.f;
#pragma unroll
    for (int k = 0; k < 64; ++k) acc += xs[r][k] * Ws[k][col];
    y[(size_t)(row0 + r) * DIM + col] = acc;
  }
}

// ---------------- out[n][:] = b ----------------
__global__ __launch_bounds__(256) void init_out(
    float* __restrict__ out, const float* __restrict__ b) {
  int t = blockIdx.x * 256 + threadIdx.x;  // float4 index
  if (t < N_NODES * (DIM / 4)) {
    const float4* b4 = (const float4*)b;
    ((float4*)out)[t] = b4[t & 15];
  }
}

// ---------------- scatter: out[dst] += y[src] * norm ----------------
// 16 lanes per edge, one float4 each.
__global__ __launch_bounds__(256) void scatter_kernel(
    const int* __restrict__ src, const int* __restrict__ dst,
    const float* __restrict__ deg_out, const float* __restrict__ deg_in,
    const float* __restrict__ y, float* __restrict__ out) {
  int t = blockIdx.x * 256 + threadIdx.x;
  int e = t >> 4;
  if (e >= N_EDGES) return;
  int lane = t & 15;
  int s = src[e];
  int d = dst[e];
  float norm = rsqrtf(fmaxf(deg_out[s], 1.f) * fmaxf(deg_in[d], 1.f));
  float4 v = ((const float4*)(y + (size_t)s * DIM))[lane];
  float* o = out + (size_t)d * DIM + lane * 4;
  unsafeAtomicAdd(o + 0, v.x * norm);
  unsafeAtomicAdd(o + 1, v.y * norm);
  unsafeAtomicAdd(o + 2, v.z * norm);
  unsafeAtomicAdd(o + 3, v.w * norm);
}

extern "C" void kernel_launch(void* const* d_in, const int* in_sizes, int n_in,
                              void* d_out, int out_size, void* d_ws, size_t ws_size,
                              hipStream_t stream) {
  const float* x = (const float*)d_in[0];
  const int* edge_index = (const int*)d_in[1];  // [2][E] flat
  const float* W = (const float*)d_in[2];
  const float* b = (const float*)d_in[3];
  float* out = (float*)d_out;

  const int* src = edge_index;
  const int* dst = edge_index + N_EDGES;

  // workspace layout: deg_out [N], deg_in [N], y [N*64]
  float* deg_out = (float*)d_ws;
  float* deg_in = deg_out + N_NODES;
  float* y = deg_in + N_NODES;

  hipMemsetAsync(deg_out, 0, 2 * N_NODES * sizeof(float), stream);

  deg_kernel<<<(N_EDGES + 255) / 256, 256, 0, stream>>>(src, dst, deg_out, deg_in);

  gemm_xw<<<(N_NODES + 63) / 64, 256, 0, stream>>>(x, W, y);

  init_out<<<(N_NODES * (DIM / 4) + 255) / 256, 256, 0, stream>>>(out, b);

  scatter_kernel<<<((size_t)N_EDGES * 16 + 255) / 256, 256, 0, stream>>>(
      src, dst, deg_out, deg_in, y, out);
}

// Round 2
// 339.935 us; speedup vs baseline: 3.7074x; 3.7074x over previous
//
#include <hip/hip_runtime.h>

#define N_NODES 100000
#define N_EDGES 1200000
#define DIM 64
#define N_SCAN_BLOCKS ((N_NODES + 255) / 256)  // 391

// ---------------- degree histogram (int atomics) ----------------
__global__ __launch_bounds__(256) void deg_kernel(
    const int* __restrict__ src, const int* __restrict__ dst,
    int* __restrict__ deg_out_i, int* __restrict__ deg_in_i) {
  int e = blockIdx.x * 256 + threadIdx.x;
  if (e < N_EDGES) {
    atomicAdd(&deg_out_i[src[e]], 1);
    atomicAdd(&deg_in_i[dst[e]], 1);
  }
}

// ---------------- scan pass 1: per-block exclusive scan of deg_in + rs tables ----
__global__ __launch_bounds__(256) void scan1(
    const int* __restrict__ deg_in_i, const int* __restrict__ deg_out_i,
    int* __restrict__ row_ptr, int* __restrict__ blocksums,
    float* __restrict__ rs_out, float* __restrict__ rs_in) {
  int i = blockIdx.x * 256 + threadIdx.x;
  int v = 0;
  if (i < N_NODES) {
    int di = deg_in_i[i];
    v = di;
    rs_in[i] = rsqrtf(fmaxf((float)di, 1.f));
    rs_out[i] = rsqrtf(fmaxf((float)deg_out_i[i], 1.f));
  }
  int lane = threadIdx.x & 63;
  int wid = threadIdx.x >> 6;
  int incl = v;
#pragma unroll
  for (int off = 1; off < 64; off <<= 1) {
    int n = __shfl_up(incl, off, 64);
    if (lane >= off) incl += n;
  }
  __shared__ int wsum[4];
  if (lane == 63) wsum[wid] = incl;
  __syncthreads();
  int wofs = 0;
  for (int w = 0; w < wid; ++w) wofs += wsum[w];
  if (i < N_NODES) row_ptr[i] = wofs + incl - v;
  if (threadIdx.x == 0)
    blocksums[blockIdx.x] = wsum[0] + wsum[1] + wsum[2] + wsum[3];
}

// ---------------- scan pass 2: exclusive scan of 391 block sums (1 block) ------
__global__ __launch_bounds__(512) void scan2(int* __restrict__ blocksums) {
  int i = threadIdx.x;
  int v = (i < N_SCAN_BLOCKS) ? blocksums[i] : 0;
  int lane = i & 63;
  int wid = i >> 6;
  int incl = v;
#pragma unroll
  for (int off = 1; off < 64; off <<= 1) {
    int n = __shfl_up(incl, off, 64);
    if (lane >= off) incl += n;
  }
  __shared__ int wsum[8];
  if (lane == 63) wsum[wid] = incl;
  __syncthreads();
  int wofs = 0;
  for (int w = 0; w < wid; ++w) wofs += wsum[w];
  if (i < N_SCAN_BLOCKS) blocksums[i] = wofs + incl - v;
}

// ---------------- scan pass 3: add block offsets ----------------
__global__ __launch_bounds__(256) void scan3(
    int* __restrict__ row_ptr, const int* __restrict__ blocksums) {
  int i = blockIdx.x * 256 + threadIdx.x;
  if (i < N_NODES) row_ptr[i] += blocksums[blockIdx.x];
}

// ---------------- y = (x @ W) * rs_out[row] ----------------
__global__ __launch_bounds__(256) void gemm_xw(
    const float* __restrict__ x, const float* __restrict__ W,
    const float* __restrict__ rs_out, float* __restrict__ y) {
  __shared__ float Ws[64][64];
  __shared__ float xs[64][64];
  int row0 = blockIdx.x * 64;

  const float4* W4 = (const float4*)W;
  float4* Ws4 = (float4*)&Ws[0][0];
  for (int i = threadIdx.x; i < 64 * 16; i += 256) Ws4[i] = W4[i];

  int nrows = N_NODES - row0;
  if (nrows > 64) nrows = 64;
  const float4* x4 = (const float4*)(x + (size_t)row0 * DIM);
  float4* xs4 = (float4*)&xs[0][0];
  for (int i = threadIdx.x; i < nrows * 16; i += 256) xs4[i] = x4[i];
  __syncthreads();

  int col = threadIdx.x & 63;
  int rg = threadIdx.x >> 6;  // wave id 0..3; wave handles rows r = rg + 4*j
  float acc[16];
#pragma unroll
  for (int j = 0; j < 16; ++j) acc[j] = 0.f;
  for (int k = 0; k < 64; ++k) {
    float w = Ws[k][col];
#pragma unroll
    for (int j = 0; j < 16; ++j) acc[j] += xs[rg + 4 * j][k] * w;
  }
#pragma unroll
  for (int j = 0; j < 16; ++j) {
    int r = rg + 4 * j;
    if (r < nrows)
      y[(size_t)(row0 + r) * DIM + col] = acc[j] * rs_out[row0 + r];
  }
}

// ---------------- CSR fill: row_ptr becomes segment END after this ------------
__global__ __launch_bounds__(256) void csr_fill(
    const int* __restrict__ src, const int* __restrict__ dst,
    int* __restrict__ row_ptr, int* __restrict__ csr_src) {
  int e = blockIdx.x * 256 + threadIdx.x;
  if (e < N_EDGES) {
    int d = dst[e];
    int pos = atomicAdd(&row_ptr[d], 1);
    csr_src[pos] = src[e];
  }
}

// ---------------- gather: out[n] = rs_in[n] * sum_e y[csr_src[e]] + b ---------
// One 64-lane wave per node; lane = column. 4 nodes per 256-thread block.
__global__ __launch_bounds__(256) void gather_kernel(
    const int* __restrict__ row_end, const int* __restrict__ deg_in_i,
    const int* __restrict__ csr_src, const float* __restrict__ y,
    const float* __restrict__ rs_in, const float* __restrict__ b,
    float* __restrict__ out) {
  int n = blockIdx.x * 4 + (threadIdx.x >> 6);
  if (n >= N_NODES) return;
  int lane = threadIdx.x & 63;
  int end = row_end[n];
  int beg = end - deg_in_i[n];
  float acc = 0.f;
  int e = beg;
  for (; e + 3 < end; e += 4) {
    int s0 = csr_src[e + 0];
    int s1 = csr_src[e + 1];
    int s2 = csr_src[e + 2];
    int s3 = csr_src[e + 3];
    float v0 = y[(size_t)s0 * DIM + lane];
    float v1 = y[(size_t)s1 * DIM + lane];
    float v2 = y[(size_t)s2 * DIM + lane];
    float v3 = y[(size_t)s3 * DIM + lane];
    acc += v0 + v1 + v2 + v3;
  }
  for (; e < end; ++e) {
    int s = csr_src[e];
    acc += y[(size_t)s * DIM + lane];
  }
  out[(size_t)n * DIM + lane] = acc * rs_in[n] + b[lane];
}

extern "C" void kernel_launch(void* const* d_in, const int* in_sizes, int n_in,
                              void* d_out, int out_size, void* d_ws, size_t ws_size,
                              hipStream_t stream) {
  const float* x = (const float*)d_in[0];
  const int* edge_index = (const int*)d_in[1];  // [2][E] flat
  const float* W = (const float*)d_in[2];
  const float* b = (const float*)d_in[3];
  float* out = (float*)d_out;

  const int* src = edge_index;
  const int* dst = edge_index + N_EDGES;

  // workspace layout (all 4-byte elems):
  int* deg_out_i = (int*)d_ws;                 // N
  int* deg_in_i = deg_out_i + N_NODES;         // N
  int* row_ptr = deg_in_i + N_NODES;           // N
  int* blocksums = row_ptr + N_NODES;          // 512
  float* rs_out = (float*)(blocksums + 512);   // N
  float* rs_in = rs_out + N_NODES;             // N
  int* csr_src = (int*)(rs_in + N_NODES);      // E
  float* y = (float*)(csr_src + N_EDGES);      // N*64

  hipMemsetAsync(deg_out_i, 0, 2 * N_NODES * sizeof(int), stream);

  deg_kernel<<<(N_EDGES + 255) / 256, 256, 0, stream>>>(src, dst, deg_out_i, deg_in_i);

  scan1<<<N_SCAN_BLOCKS, 256, 0, stream>>>(deg_in_i, deg_out_i, row_ptr, blocksums,
                                           rs_out, rs_in);
  scan2<<<1, 512, 0, stream>>>(blocksums);
  scan3<<<N_SCAN_BLOCKS, 256, 0, stream>>>(row_ptr, blocksums);

  gemm_xw<<<(N_NODES + 63) / 64, 256, 0, stream>>>(x, W, rs_out, y);

  csr_fill<<<(N_EDGES + 255) / 256, 256, 0, stream>>>(src, dst, row_ptr, csr_src);

  gather_kernel<<<(N_NODES + 3) / 4, 256, 0, stream>>>(row_ptr, deg_in_i, csr_src, y,
                                                       rs_in, b, out);
}